// Round 7
// baseline (147.417 us; speedup 1.0000x reference)
//
#include <hip/hip_runtime.h>
#include <math.h>

#define Bn 64
#define Rr 36
#define Ww 40
#define Dd 1024
#define GM 2304   // Bn*Rr
#define GN 2560   // Bn*Ww
#define GP 41     // gacc pitch in floats (gcd(9,32)=1 -> conflict-free both axes)
#define NCONV 4864  // (GM*Dd + GN*Dd)/4/256
#define EPSf 1e-8f

typedef unsigned short u16;
typedef __attribute__((ext_vector_type(8))) short bf16x8;
typedef __attribute__((ext_vector_type(4))) float f32x4;

struct alignas(8) U16x4 { u16 x, y, z, w; };

__device__ inline u16 f2bf(float x) {
    unsigned int u = __float_as_uint(x);
    u += 0x7FFFu + ((u >> 16) & 1u);
    return (u16)(u >> 16);
}
__device__ inline float bf2f(u16 h) {
    return __uint_as_float(((unsigned int)h) << 16);
}

// ================= prep: convert (blocks < NCONV) + grams-from-fp32 =================
// gram blocks read fp32 im/s directly (row-clamped); garbage in rows>=n or masked
// word-rows only touches Gram cells that are multiplied by exactly-zero attention.
__global__ __launch_bounds__(256) void prep_kernel(const float* __restrict__ im,
                                                   const float* __restrict__ s,
                                                   const int* __restrict__ s_l,
                                                   u16* __restrict__ Ab,
                                                   u16* __restrict__ Bb,
                                                   float* __restrict__ SS,
                                                   float* __restrict__ II) {
    __shared__ float red[3][64][37];
    int b = blockIdx.x, t = threadIdx.x;
    if (b < NCONV) {
        const int nA4 = GM * Dd / 4;
        int idx = b * 256 + t;
        if (idx < nA4) {
            float4 v = *(const float4*)(im + (size_t)idx * 4);
            U16x4 o = {f2bf(v.x), f2bf(v.y), f2bf(v.z), f2bf(v.w)};
            *(U16x4*)(Ab + (size_t)idx * 4) = o;
        } else {
            int i2 = idx - nA4;
            int f = i2 * 4;
            int row = f >> 10;
            int j = row / Ww, w = row - j * Ww;
            U16x4 o = {0, 0, 0, 0};
            if (w < s_l[j]) {
                float4 v = *(const float4*)(s + (size_t)f);
                o.x = f2bf(v.x); o.y = f2bf(v.y); o.z = f2bf(v.z); o.w = f2bf(v.w);
            }
            *(U16x4*)(Bb + (size_t)i2 * 4) = o;
        }
        return;
    }
    // ---- gram branch (128 blocks) ----
    int gb = b - NCONV;
    bool isS = gb < Bn;
    int idx = isS ? gb : gb - Bn;
    int n = isS ? Ww : Rr;
    const float* basef = isS ? (s + (size_t)idx * Ww * Dd) : (im + (size_t)idx * Rr * Dd);
    float* outp = isS ? (SS + (size_t)idx * Ww * Ww) : (II + (size_t)idx * Rr * Rr);
    int lane = t & 63, wid = t >> 6;
    int frow = lane & 15, fk = (lane >> 4) * 8;

    f32x4 acc[3][3];
    for (int m = 0; m < 3; ++m)
        for (int p = 0; p < 3; ++p) acc[m][p] = (f32x4){0.f, 0.f, 0.f, 0.f};

    for (int ks = 0; ks < 8; ++ks) {
        int k0 = wid * 256 + ks * 32 + fk;
        bf16x8 f[3];
        for (int m = 0; m < 3; ++m) {
            int rr = m * 16 + frow;
            if (rr >= n) rr = n - 1;          // clamp: stay in-bounds of input
            const float* p = basef + (size_t)rr * Dd + k0;
            float4 v0 = *(const float4*)p;
            float4 v1 = *(const float4*)(p + 4);
            bf16x8 fv;
            fv[0] = (short)f2bf(v0.x); fv[1] = (short)f2bf(v0.y);
            fv[2] = (short)f2bf(v0.z); fv[3] = (short)f2bf(v0.w);
            fv[4] = (short)f2bf(v1.x); fv[5] = (short)f2bf(v1.y);
            fv[6] = (short)f2bf(v1.z); fv[7] = (short)f2bf(v1.w);
            f[m] = fv;
        }
        for (int m = 0; m < 3; ++m)
            for (int p = 0; p < 3; ++p)
                acc[m][p] = __builtin_amdgcn_mfma_f32_16x16x32_bf16(f[m], f[p], acc[m][p], 0, 0, 0);
    }
    if (wid) {
        for (int m = 0; m < 3; ++m)
            for (int p = 0; p < 3; ++p)
                for (int q = 0; q < 4; ++q)
                    red[wid - 1][lane][(m * 3 + p) * 4 + q] = acc[m][p][q];
    }
    __syncthreads();
    if (wid == 0) {
        for (int wv = 0; wv < 3; ++wv)
            for (int m = 0; m < 3; ++m)
                for (int p = 0; p < 3; ++p)
                    for (int q = 0; q < 4; ++q)
                        acc[m][p][q] += red[wv][lane][(m * 3 + p) * 4 + q];
        int crow = (lane >> 4) * 4, ccol = lane & 15;
        for (int m = 0; m < 3; ++m)
            for (int p = 0; p < 3; ++p)
                for (int q = 0; q < 4; ++q) {
                    int row = m * 16 + crow + q;
                    int col = p * 16 + ccol;
                    if (row < n && col < n) outp[row * n + col] = acc[m][p][q];
                }
    }
}

// ================= fused GEMM + pair kernel =================
// grid (j, i), 256 threads = 4 waves. Wave wid computes K quarter of the 36x40
// G tile via MFMA (frag rows >=36/40 read adjacent ws data - masked at reduce).
__global__ __launch_bounds__(256) void fused_kernel(const u16* __restrict__ Ab,
                                                    const u16* __restrict__ Bb,
                                                    const float* __restrict__ SS,
                                                    const float* __restrict__ II,
                                                    const int* __restrict__ s_l,
                                                    float* __restrict__ score1,
                                                    float* __restrict__ score2,
                                                    float* __restrict__ dAp,
                                                    float* __restrict__ dBp) {
    int j = blockIdx.x, i = blockIdx.y;
    int t = threadIdx.x, lane = t & 63, wid = t >> 6;
    __shared__ __align__(16) float gacc[Rr * GP];     // fp32 G tile, pitch 41
    __shared__ __align__(16) u16 attA[Ww * Rr];       // [w][r] unnormalized e (bf16)
    __shared__ __align__(16) u16 attB[Rr * Ww];       // [r][w] unnormalized e (bf16)
    __shared__ float invA[Ww], invB[Rr], sA[Rr], sB[Ww];
    __shared__ __align__(16) float qpA[360], qpB[360];
    int L = s_l[j];

    // early diag loads (held in registers through the matmul)
    float iid = 0.f, ssd = 0.f;
    if (wid == 0 && lane < Rr) iid = II[(size_t)i * Rr * Rr + lane * (Rr + 1)];
    if (wid == 1 && lane < Ww) ssd = SS[(size_t)j * Ww * Ww + lane * (Ww + 1)];

    // ---- phase M: K-split MFMA matmul ----
    const u16* Abase = Ab + (size_t)(i * Rr) * Dd;
    const u16* Bbase = Bb + (size_t)(j * Ww) * Dd;
    int frow = lane & 15, fk = (lane >> 4) * 8;
    f32x4 acc[3][3];
    for (int m = 0; m < 3; ++m)
        for (int p = 0; p < 3; ++p) acc[m][p] = (f32x4){0.f, 0.f, 0.f, 0.f};
#pragma unroll
    for (int ks = 0; ks < 8; ++ks) {
        int k0 = wid * 256 + ks * 32 + fk;
        bf16x8 fa[3], fb[3];
#pragma unroll
        for (int m = 0; m < 3; ++m)
            fa[m] = *(const bf16x8*)(Abase + (size_t)(m * 16 + frow) * Dd + k0);
#pragma unroll
        for (int p = 0; p < 3; ++p)
            fb[p] = *(const bf16x8*)(Bbase + (size_t)(p * 16 + frow) * Dd + k0);
#pragma unroll
        for (int m = 0; m < 3; ++m)
#pragma unroll
            for (int p = 0; p < 3; ++p)
                acc[m][p] = __builtin_amdgcn_mfma_f32_16x16x32_bf16(fa[m], fb[p], acc[m][p], 0, 0, 0);
    }
    // ---- serialized cross-wave reduce into gacc (each wave's cells are unique) ----
    int crow = (lane >> 4) * 4, ccol = lane & 15;
    for (int wv = 0; wv < 4; ++wv) {
        if (wid == wv) {
            for (int m = 0; m < 3; ++m)
                for (int p = 0; p < 3; ++p)
                    for (int q = 0; q < 4; ++q) {
                        int r = m * 16 + crow + q, w = p * 16 + ccol;
                        if (r < Rr && w < Ww) {
                            if (wv == 0) gacc[r * GP + w] = acc[m][p][q];
                            else gacc[r * GP + w] += acc[m][p][q];
                        }
                    }
        }
        __syncthreads();
    }
    // ---- norms ----
    if (wid == 1 && lane < Ww) {
        float sum = 0.f;
#pragma unroll 6
        for (int r = 0; r < Rr; ++r) {
            float x = gacc[r * GP + lane];
            x = x < 0.f ? 0.1f * x : x;
            sum += x * x;
        }
        invA[lane] = 6.f / (sqrtf(sum) + EPSf);
    }
    if (wid == 0 && lane < Rr) {
        float sum = 0.f;
#pragma unroll 8
        for (int w = 0; w < Ww; ++w) {
            float x = gacc[lane * GP + w];
            x = x < 0.f ? 0.1f * x : x;
            sum += x * x;
        }
        invB[lane] = 9.f / (sqrtf(sum) + EPSf);
    }
    __syncthreads();
    // ---- softmaxes (no-max: args bounded by 6/9) + fused dot ----
    float dot = 0.f, myinv = 0.f;
    if (wid == 0 && lane < Rr) {
        float ssum = 0.f;
#pragma unroll 8
        for (int w = 0; w < Ww; ++w) {
            float e = 0.f;
            if (w < L) {
                float gx = gacc[lane * GP + w];
                float x = gx < 0.f ? 0.1f * gx : gx;
                e = __expf(x * invA[w]);
                dot += e * gx;
            }
            attA[w * Rr + lane] = f2bf(e);
            ssum += e;
        }
        myinv = 1.f / ssum;
        dot *= myinv;
        sA[lane] = myinv;
    }
    if (wid == 1 && lane < Ww) {
        float ssum = 0.f;
#pragma unroll 6
        for (int r = 0; r < Rr; ++r) {
            float gx = gacc[r * GP + lane];
            float x = gx < 0.f ? 0.1f * gx : gx;
            float e = __expf(x * invB[lane == lane ? r : r]);  // invB[r]
            e = __expf(x * invB[r]);
            dot += e * gx;
            attB[r * Ww + lane] = f2bf(e);
            ssum += e;
        }
        myinv = 1.f / ssum;
        dot *= myinv;
        sB[lane] = myinv;
    }
    __syncthreads();
    // ---- quadratic forms: 90 A-jobs on t<90, 90 B-jobs on 128<=t<218 ----
    if (t < 90) {
        int wg = t / 9, rg = t - wg * 9;
        float a4[4][4];
#pragma unroll
        for (int x = 0; x < 4; ++x)
#pragma unroll
            for (int y = 0; y < 4; ++y) a4[x][y] = 0.f;
        const float* SSp = SS + (size_t)j * Ww * Ww + wg * 4;
#pragma unroll 4
        for (int w = 0; w < Ww; ++w) {
            ushort4 a16 = *(const ushort4*)&attA[w * Rr + rg * 4];
            float4 sv = *(const float4*)(SSp + (size_t)w * Ww);
            float av0 = bf2f(a16.x), av1 = bf2f(a16.y), av2 = bf2f(a16.z), av3 = bf2f(a16.w);
            a4[0][0] += av0 * sv.x; a4[0][1] += av0 * sv.y; a4[0][2] += av0 * sv.z; a4[0][3] += av0 * sv.w;
            a4[1][0] += av1 * sv.x; a4[1][1] += av1 * sv.y; a4[1][2] += av1 * sv.z; a4[1][3] += av1 * sv.w;
            a4[2][0] += av2 * sv.x; a4[2][1] += av2 * sv.y; a4[2][2] += av2 * sv.z; a4[2][3] += av2 * sv.w;
            a4[3][0] += av3 * sv.x; a4[3][1] += av3 * sv.y; a4[3][2] += av3 * sv.z; a4[3][3] += av3 * sv.w;
        }
        float qv0 = 0.f, qv1 = 0.f, qv2 = 0.f, qv3 = 0.f;
#pragma unroll
        for (int wj = 0; wj < 4; ++wj) {
            ushort4 b16 = *(const ushort4*)&attA[(wg * 4 + wj) * Rr + rg * 4];
            qv0 += bf2f(b16.x) * a4[0][wj];
            qv1 += bf2f(b16.y) * a4[1][wj];
            qv2 += bf2f(b16.z) * a4[2][wj];
            qv3 += bf2f(b16.w) * a4[3][wj];
        }
        qpA[(rg * 4 + 0) * 10 + wg] = qv0;
        qpA[(rg * 4 + 1) * 10 + wg] = qv1;
        qpA[(rg * 4 + 2) * 10 + wg] = qv2;
        qpA[(rg * 4 + 3) * 10 + wg] = qv3;
    } else if (t >= 128 && t < 218) {
        int job = t - 128;
        int rg = job / 10, wg = job - rg * 10;
        float a4[4][4];
#pragma unroll
        for (int x = 0; x < 4; ++x)
#pragma unroll
            for (int y = 0; y < 4; ++y) a4[x][y] = 0.f;
        const float* IIp = II + (size_t)i * Rr * Rr + rg * 4;
#pragma unroll 4
        for (int r = 0; r < Rr; ++r) {
            ushort4 b16 = *(const ushort4*)&attB[r * Ww + wg * 4];
            float4 iv = *(const float4*)(IIp + (size_t)r * Rr);
            float bv0 = bf2f(b16.x), bv1 = bf2f(b16.y), bv2 = bf2f(b16.z), bv3 = bf2f(b16.w);
            a4[0][0] += bv0 * iv.x; a4[0][1] += bv0 * iv.y; a4[0][2] += bv0 * iv.z; a4[0][3] += bv0 * iv.w;
            a4[1][0] += bv1 * iv.x; a4[1][1] += bv1 * iv.y; a4[1][2] += bv1 * iv.z; a4[1][3] += bv1 * iv.w;
            a4[2][0] += bv2 * iv.x; a4[2][1] += bv2 * iv.y; a4[2][2] += bv2 * iv.z; a4[2][3] += bv2 * iv.w;
            a4[3][0] += bv3 * iv.x; a4[3][1] += bv3 * iv.y; a4[3][2] += bv3 * iv.z; a4[3][3] += bv3 * iv.w;
        }
        float qv0 = 0.f, qv1 = 0.f, qv2 = 0.f, qv3 = 0.f;
#pragma unroll
        for (int rj = 0; rj < 4; ++rj) {
            ushort4 b2 = *(const ushort4*)&attB[(rg * 4 + rj) * Ww + wg * 4];
            qv0 += bf2f(b2.x) * a4[0][rj];
            qv1 += bf2f(b2.y) * a4[1][rj];
            qv2 += bf2f(b2.z) * a4[2][rj];
            qv3 += bf2f(b2.w) * a4[3][rj];
        }
        qpB[(wg * 4 + 0) * 9 + rg] = qv0;
        qpB[(wg * 4 + 1) * 9 + rg] = qv1;
        qpB[(wg * 4 + 2) * 9 + rg] = qv2;
        qpB[(wg * 4 + 3) * 9 + rg] = qv3;
    }
    __syncthreads();
    // ---- LSE (waves 0,1) + diag coefficients (waves 2,3) ----
    if (wid == 0) {
        float e1 = 0.f;
        if (lane < Rr) {
            float q = 0.f;
#pragma unroll
            for (int wg = 0; wg < 10; ++wg) q += qpA[lane * 10 + wg];
            q *= myinv * myinv;
            float s1 = dot / fmaxf(sqrtf(iid) * sqrtf(fmaxf(q, 0.f)), EPSf);
            e1 = __expf(6.f * s1);
        }
#pragma unroll
        for (int off = 1; off < 64; off <<= 1) e1 += __shfl_xor(e1, off);
        if (lane == 0) score1[i * Bn + j] = __logf(e1) * (1.f / 6.f);
    } else if (wid == 1) {
        float e2 = 0.f;
        if (lane < Ww) {
            float q = 0.f;
#pragma unroll
            for (int rg = 0; rg < 9; ++rg) q += qpB[lane * 9 + rg];
            q *= myinv * myinv;
            float s2 = dot / fmaxf(sqrtf(ssd) * sqrtf(fmaxf(q, 0.f)), EPSf);
            e2 = (lane < L) ? __expf(6.f * s2) : 0.f;
        }
#pragma unroll
        for (int off = 1; off < 64; off <<= 1) e2 += __shfl_xor(e2, off);
        if (lane == 0) score2[i * Bn + j] = __logf(e2) * (1.f / 6.f);
    } else if (i == j) {
        if (wid == 2 && lane < Ww) {
            float sum = 0.f;
#pragma unroll 6
            for (int r = 0; r < Rr; ++r) sum += bf2f(attA[lane * Rr + r]) * sA[r];
            dAp[i * Ww + lane] = sum * (1.f / (float)Rr);
        } else if (wid == 3 && lane < Rr) {
            float sum = 0.f;
            for (int w = 0; w < L; ++w) sum += bf2f(attB[lane * Ww + w]) * sB[w];
            dBp[i * Rr + lane] = sum / (float)L;
        }
    }
}

// ================= diagonal outputs + fused hinge loss =================
__global__ __launch_bounds__(256) void diag_out_kernel(const u16* __restrict__ Ab,
                                                       const u16* __restrict__ Bb,
                                                       const int* __restrict__ s_l,
                                                       const float* __restrict__ dA,
                                                       const float* __restrict__ dB,
                                                       const float* __restrict__ score1,
                                                       const float* __restrict__ score2,
                                                       float* __restrict__ out) {
    int t = threadIdx.x;
    if (blockIdx.y == 4) {
        if (blockIdx.x != 0) return;
        __shared__ float sc[Bn][Bn + 1];
        for (int idx = t; idx < Bn * Bn; idx += 256)
            sc[idx >> 6][idx & 63] = 0.5f * (score1[idx] + score2[idx]);
        __syncthreads();
        if (t < 64) {
            float dt = sc[t][t];
            float rowmax = 0.f, colmax = 0.f;
            for (int k = 0; k < Bn; ++k) {
                if (k != t) {
                    rowmax = fmaxf(rowmax, 0.2f + sc[t][k] - dt);
                    colmax = fmaxf(colmax, 0.2f + sc[k][t] - dt);
                }
            }
            float v = rowmax + colmax;
            for (int off = 32; off; off >>= 1) v += __shfl_down(v, off);
            if (t == 0) out[0] = v;
        }
        return;
    }
    int i = blockIdx.x;
    int d = blockIdx.y * 256 + t;
    int L = s_l[i];
    __shared__ float aw[Ww], br[Rr];
    if (t < Ww) aw[t] = dA[i * Ww + t];
    if (t >= 64 && t < 64 + Rr) br[t - 64] = dB[i * Rr + (t - 64)];
    __syncthreads();
    float acc1 = 0.f;
    for (int w = 0; w < L; ++w) acc1 += aw[w] * bf2f(Bb[((size_t)i * Ww + w) * Dd + d]);
    out[1 + (size_t)i * Dd + d] = acc1;
    float acc2 = 0.f;
    for (int r = 0; r < Rr; ++r) acc2 += br[r] * bf2f(Ab[((size_t)i * Rr + r) * Dd + d]);
    out[1 + (size_t)Bn * Dd + (size_t)i * Dd + d] = acc2;
}

extern "C" void kernel_launch(void* const* d_in, const int* in_sizes, int n_in,
                              void* d_out, int out_size, void* d_ws, size_t ws_size,
                              hipStream_t stream) {
    const float* im = (const float*)d_in[0];
    const float* s = (const float*)d_in[1];
    const int* s_l = (const int*)d_in[2];
    float* out = (float*)d_out;

    const size_t nAb = (size_t)GM * Dd;
    const size_t nBb = (size_t)GN * Dd;
    u16* Ab = (u16*)d_ws;
    u16* Bb = Ab + nAb;
    float* SS = (float*)(Bb + nBb);
    float* II = SS + (size_t)Bn * Ww * Ww;
    float* score1 = II + (size_t)Bn * Rr * Rr;
    float* score2 = score1 + Bn * Bn;
    float* dA = score2 + Bn * Bn;
    float* dB = dA + Bn * Ww;

    prep_kernel<<<NCONV + 2 * Bn, 256, 0, stream>>>(im, s, s_l, Ab, Bb, SS, II);

    dim3 fgrid(Bn, Bn);
    fused_kernel<<<fgrid, 256, 0, stream>>>(Ab, Bb, SS, II, s_l, score1, score2, dA, dB);

    dim3 dgrid(Bn, 5);
    diag_out_kernel<<<dgrid, 256, 0, stream>>>(Ab, Bb, s_l, dA, dB, score1, score2, out);
}

// Round 8
// 75.828 us; speedup vs baseline: 1.9441x; 1.9441x over previous
//
#include <hip/hip_runtime.h>
#include <math.h>

#define Bn 64
#define Rr 36
#define Ww 40
#define Dd 1024
#define GM 2304   // Bn*Rr
#define GN 2560   // Bn*Ww
#define NCONV 4864  // (GM*Dd + GN*Dd)/4/256
#define PAD 72      // att LDS pitch (u16): 144B rows -> ~2-way banks on b128 frag reads
#define SBP 64      // SSb/IIb global pitch (u16)
#define EPSf 1e-8f

typedef unsigned short u16;
typedef __attribute__((ext_vector_type(8))) short bf16x8;
typedef __attribute__((ext_vector_type(4))) float f32x4;

struct alignas(8) U16x4 { u16 x, y, z, w; };

__device__ inline u16 f2bf(float x) {
    unsigned int u = __float_as_uint(x);
    u += 0x7FFFu + ((u >> 16) & 1u);
    return (u16)(u >> 16);
}
__device__ inline float bf2f(u16 h) {
    return __uint_as_float(((unsigned int)h) << 16);
}

__device__ __forceinline__ void gl_lds16(const u16* g, u16* l) {
    __builtin_amdgcn_global_load_lds(
        (const __attribute__((address_space(1))) void*)g,
        (__attribute__((address_space(3))) void*)l, 16, 0, 0);
}

// ================= prep: convert + grams (bf16-padded + fp32 diag) =================
__global__ __launch_bounds__(256) void prep_kernel(const float* __restrict__ im,
                                                   const float* __restrict__ s,
                                                   const int* __restrict__ s_l,
                                                   u16* __restrict__ Ab,
                                                   u16* __restrict__ Bb,
                                                   u16* __restrict__ SSb,
                                                   u16* __restrict__ IIb,
                                                   float* __restrict__ SSd,
                                                   float* __restrict__ IId) {
    __shared__ float red[3][64][37];
    int b = blockIdx.x, t = threadIdx.x;
    if (b < NCONV) {
        const int nA4 = GM * Dd / 4;
        int idx = b * 256 + t;
        if (idx < nA4) {
            float4 v = *(const float4*)(im + (size_t)idx * 4);
            U16x4 o = {f2bf(v.x), f2bf(v.y), f2bf(v.z), f2bf(v.w)};
            *(U16x4*)(Ab + (size_t)idx * 4) = o;
        } else {
            int i2 = idx - nA4;
            int f = i2 * 4;
            int row = f >> 10;
            int j = row / Ww, w = row - j * Ww;
            U16x4 o = {0, 0, 0, 0};
            if (w < s_l[j]) {
                float4 v = *(const float4*)(s + (size_t)f);
                o.x = f2bf(v.x); o.y = f2bf(v.y); o.z = f2bf(v.z); o.w = f2bf(v.w);
            }
            *(U16x4*)(Bb + (size_t)i2 * 4) = o;
        }
        return;
    }
    // ---- gram branch (128 blocks); rows clamped to stay in-bounds; garbage cells
    // land only where attention weights are exactly zero.
    int gb = b - NCONV;
    bool isS = gb < Bn;
    int idx = isS ? gb : gb - Bn;
    int n = isS ? Ww : Rr;
    const float* basef = isS ? (s + (size_t)idx * Ww * Dd) : (im + (size_t)idx * Rr * Dd);
    u16* outb = isS ? (SSb + (size_t)idx * 48 * SBP) : (IIb + (size_t)idx * 48 * SBP);
    float* outd = isS ? (SSd + (size_t)idx * Ww) : (IId + (size_t)idx * Rr);
    int lane = t & 63, wid = t >> 6;
    int frow = lane & 15, fk = (lane >> 4) * 8;

    f32x4 acc[3][3];
    for (int m = 0; m < 3; ++m)
        for (int p = 0; p < 3; ++p) acc[m][p] = (f32x4){0.f, 0.f, 0.f, 0.f};

    for (int ks = 0; ks < 8; ++ks) {
        int k0 = wid * 256 + ks * 32 + fk;
        bf16x8 f[3];
        for (int m = 0; m < 3; ++m) {
            int rr = m * 16 + frow;
            if (rr >= n) rr = n - 1;
            const float* p = basef + (size_t)rr * Dd + k0;
            float4 v0 = *(const float4*)p;
            float4 v1 = *(const float4*)(p + 4);
            bf16x8 fv;
            fv[0] = (short)f2bf(v0.x); fv[1] = (short)f2bf(v0.y);
            fv[2] = (short)f2bf(v0.z); fv[3] = (short)f2bf(v0.w);
            fv[4] = (short)f2bf(v1.x); fv[5] = (short)f2bf(v1.y);
            fv[6] = (short)f2bf(v1.z); fv[7] = (short)f2bf(v1.w);
            f[m] = fv;
        }
        for (int m = 0; m < 3; ++m)
            for (int p = 0; p < 3; ++p)
                acc[m][p] = __builtin_amdgcn_mfma_f32_16x16x32_bf16(f[m], f[p], acc[m][p], 0, 0, 0);
    }
    if (wid) {
        for (int m = 0; m < 3; ++m)
            for (int p = 0; p < 3; ++p)
                for (int q = 0; q < 4; ++q)
                    red[wid - 1][lane][(m * 3 + p) * 4 + q] = acc[m][p][q];
    }
    __syncthreads();
    if (wid == 0) {
        for (int wv = 0; wv < 3; ++wv)
            for (int m = 0; m < 3; ++m)
                for (int p = 0; p < 3; ++p)
                    for (int q = 0; q < 4; ++q)
                        acc[m][p][q] += red[wv][lane][(m * 3 + p) * 4 + q];
        int crow = (lane >> 4) * 4, ccol = lane & 15;
        for (int m = 0; m < 3; ++m)
            for (int p = 0; p < 3; ++p)
                for (int q = 0; q < 4; ++q) {
                    int row = m * 16 + crow + q;
                    int col = p * 16 + ccol;
                    float v = acc[m][p][q];
                    outb[row * SBP + col] = f2bf(v);           // rows/cols < 48 always
                    if (row == col && row < n) outd[row] = v;  // exact fp32 diag
                }
    }
}

// ================= MFMA bf16 GEMM: BK=64, XOR swizzle, double-buffered, bf16 out =====
__global__ __launch_bounds__(256) void gemm_mfma_kernel(const u16* __restrict__ Ab,
                                                        const u16* __restrict__ Bb,
                                                        u16* __restrict__ Gb) {
    __shared__ __align__(16) u16 As[2][64][64];
    __shared__ __align__(16) u16 Bs[2][128][64];
    int bn = blockIdx.x;
    int bm = blockIdx.y;
    int t = threadIdx.x;
    int lane = t & 63, wid = t >> 6;
    int wr = wid >> 1, wc = wid & 1;

    int lrow8 = lane >> 3;
    int sslot = (lane & 7) ^ lrow8;   // pre-swizzled global source, linear LDS dest
    const u16* ga = Ab + ((size_t)(bm * 64 + wid * 16) + lrow8) * Dd + sslot * 8;
    const u16* gb = Bb + ((size_t)(bn * 128 + wid * 32) + lrow8) * Dd + sslot * 8;

    f32x4 acc[2][4];
    for (int m = 0; m < 2; ++m)
        for (int n = 0; n < 4; ++n) acc[m][n] = (f32x4){0.f, 0.f, 0.f, 0.f};

    int frow = lane & 15;
    int cgr = lane >> 4;

#define STAGE(BI, KK) do { \
        gl_lds16(ga + (KK), &As[BI][wid * 16][0]); \
        gl_lds16(ga + (size_t)8 * Dd + (KK), &As[BI][wid * 16 + 8][0]); \
        gl_lds16(gb + (KK), &Bs[BI][wid * 32][0]); \
        gl_lds16(gb + (size_t)8 * Dd + (KK), &Bs[BI][wid * 32 + 8][0]); \
        gl_lds16(gb + (size_t)16 * Dd + (KK), &Bs[BI][wid * 32 + 16][0]); \
        gl_lds16(gb + (size_t)24 * Dd + (KK), &Bs[BI][wid * 32 + 24][0]); \
    } while (0)

    STAGE(0, 0);
    for (int step = 0; step < 16; ++step) {
        int cur = step & 1;
        __syncthreads();
        if (step < 15) STAGE(cur ^ 1, (step + 1) * 64);
        bf16x8 af[2][2], bf[4][2];
#pragma unroll
        for (int m = 0; m < 2; ++m) {
            int row = wr * 32 + m * 16 + frow;
#pragma unroll
            for (int ks = 0; ks < 2; ++ks) {
                int slot = (ks * 4 + cgr) ^ (row & 7);
                af[m][ks] = *(const bf16x8*)&As[cur][row][slot * 8];
            }
        }
#pragma unroll
        for (int n = 0; n < 4; ++n) {
            int row = wc * 64 + n * 16 + frow;
#pragma unroll
            for (int ks = 0; ks < 2; ++ks) {
                int slot = (ks * 4 + cgr) ^ (row & 7);
                bf[n][ks] = *(const bf16x8*)&Bs[cur][row][slot * 8];
            }
        }
#pragma unroll
        for (int ks = 0; ks < 2; ++ks)
#pragma unroll
            for (int m = 0; m < 2; ++m)
#pragma unroll
                for (int n = 0; n < 4; ++n)
                    acc[m][n] = __builtin_amdgcn_mfma_f32_16x16x32_bf16(af[m][ks], bf[n][ks], acc[m][n], 0, 0, 0);
    }
#undef STAGE

    int crow0 = bm * 64 + wr * 32 + (lane >> 4) * 4;
    int ccol0 = bn * 128 + wc * 64 + (lane & 15);
    for (int m = 0; m < 2; ++m)
        for (int q = 0; q < 4; ++q) {
            int row = crow0 + m * 16 + q;
            for (int n = 0; n < 4; ++n)
                Gb[(size_t)row * GN + ccol0 + n * 16] = f2bf(acc[m][n][q]);
        }
}

// ---- quadratic form via MFMA: q[row] = e_row^T M e_row (att: LDS bf16 [48][PAD]) ----
__device__ __forceinline__ void quad_mfma(const u16* att, const u16* M,
                                          float* qout, int nq, int lane) {
    int c = lane & 15, g4 = lane >> 4;
    f32x4 acc[3][3];
#pragma unroll
    for (int m = 0; m < 3; ++m)
#pragma unroll
        for (int p = 0; p < 3; ++p) acc[m][p] = (f32x4){0.f, 0.f, 0.f, 0.f};
#pragma unroll
    for (int ks = 0; ks < 2; ++ks) {
        bf16x8 fa[3], fb[3];
#pragma unroll
        for (int m = 0; m < 3; ++m)
            fa[m] = *(const bf16x8*)&att[(m * 16 + c) * PAD + g4 * 8 + ks * 32];
#pragma unroll
        for (int p = 0; p < 3; ++p)
            fb[p] = *(const bf16x8*)(M + (size_t)(p * 16 + c) * SBP + g4 * 8 + ks * 32);
#pragma unroll
        for (int m = 0; m < 3; ++m)
#pragma unroll
            for (int p = 0; p < 3; ++p)
                acc[m][p] = __builtin_amdgcn_mfma_f32_16x16x32_bf16(fa[m], fb[p], acc[m][p], 0, 0, 0);
    }
    // dot with e + reduce across the 16 lanes of each row group
#pragma unroll
    for (int m = 0; m < 3; ++m)
#pragma unroll
        for (int q = 0; q < 4; ++q) {
            int row = m * 16 + g4 * 4 + q;
            float sp = 0.f;
#pragma unroll
            for (int p = 0; p < 3; ++p)
                sp += acc[m][p][q] * bf2f(att[row * PAD + p * 16 + c]);
            sp += __shfl_xor(sp, 1);
            sp += __shfl_xor(sp, 2);
            sp += __shfl_xor(sp, 4);
            sp += __shfl_xor(sp, 8);
            if (c == 0 && row < nq) qout[row] = sp;
        }
}

// ================= per-pair kernel: 2 waves, MFMA quad-forms =================
__global__ __launch_bounds__(128) void pair_kernel(const u16* __restrict__ Gb,
                                                   const u16* __restrict__ SSb,
                                                   const u16* __restrict__ IIb,
                                                   const float* __restrict__ SSd,
                                                   const float* __restrict__ IId,
                                                   const int* __restrict__ s_l,
                                                   float* __restrict__ score1,
                                                   float* __restrict__ score2,
                                                   float* __restrict__ dAp,
                                                   float* __restrict__ dBp) {
    int j = blockIdx.x, i = blockIdx.y;
    int t = threadIdx.x, lane = t & 63, wid = t >> 6;
    __shared__ __align__(16) u16 glb[Rr * 44];      // g bf16, pitch 44
    __shared__ __align__(16) u16 attA[48 * PAD];    // [r][w] unnormalized e
    __shared__ __align__(16) u16 attB[48 * PAD];    // [w][r] unnormalized e
    __shared__ float invA[Ww], invB[Rr], sA[Rr], sB[Ww], qA[Rr], qB[Ww];
    int L = s_l[j];

    // ---- P0: zero att arrays; load g tile + diag norms ----
    {
        uint* za = (uint*)attA;
        uint* zb = (uint*)attB;
#pragma unroll
        for (int k = 0; k < 14; ++k) {
            int idx = t + k * 128;
            if (idx < 48 * PAD / 2) { za[idx] = 0; zb[idx] = 0; }
        }
    }
    float iid = 0.f, ssd = 0.f;
    if (wid == 0 && lane < Rr) {
        iid = IId[i * Rr + lane];
        const u16* gp = Gb + (size_t)(i * Rr + lane) * GN + j * Ww;
        uint2* dst = (uint2*)&glb[lane * 44];
#pragma unroll
        for (int q = 0; q < 5; ++q) {
            uint4 v = *(const uint4*)(gp + q * 8);
            dst[q * 2] = make_uint2(v.x, v.y);
            dst[q * 2 + 1] = make_uint2(v.z, v.w);
        }
    }
    if (wid == 1 && lane < Ww) ssd = SSd[j * Ww + lane];
    __syncthreads();

    // ---- P1: norms ----
    if (wid == 0 && lane < Rr) {
        float sum = 0.f;
#pragma unroll 8
        for (int w = 0; w < Ww; ++w) {
            float x = bf2f(glb[lane * 44 + w]);
            x = x < 0.f ? 0.1f * x : x;
            sum += x * x;
        }
        invB[lane] = 9.f / (sqrtf(sum) + EPSf);
    }
    if (wid == 1 && lane < Ww) {
        float sum = 0.f;
#pragma unroll 6
        for (int r = 0; r < Rr; ++r) {
            float x = bf2f(glb[r * 44 + lane]);
            x = x < 0.f ? 0.1f * x : x;
            sum += x * x;
        }
        invA[lane] = 6.f / (sqrtf(sum) + EPSf);
    }
    __syncthreads();

    // ---- P2: softmax (no-max; args bounded) + fused dot ----
    float dot = 0.f, myinv = 0.f;
    if (wid == 0 && lane < Rr) {
        float ssum = 0.f;
#pragma unroll 8
        for (int w = 0; w < Ww; ++w) {
            float e = 0.f;
            if (w < L) {
                float gx = bf2f(glb[lane * 44 + w]);
                float x = gx < 0.f ? 0.1f * gx : gx;
                e = __expf(x * invA[w]);
                dot += e * gx;
            }
            attA[lane * PAD + w] = f2bf(e);
            ssum += e;
        }
        myinv = 1.f / ssum;
        dot *= myinv;
        sA[lane] = myinv;
    }
    if (wid == 1 && lane < Ww) {
        float ssum = 0.f;
#pragma unroll 6
        for (int r = 0; r < Rr; ++r) {
            float gx = bf2f(glb[r * 44 + lane]);
            float x = gx < 0.f ? 0.1f * gx : gx;
            float e = __expf(x * invB[r]);
            dot += e * gx;
            attB[lane * PAD + r] = f2bf(e);
            ssum += e;
        }
        myinv = 1.f / ssum;
        dot *= myinv;
        sB[lane] = myinv;
    }
    __syncthreads();

    // ---- P3: MFMA quadratic forms (each wave consumes only its own outputs) ----
    if (wid == 0)
        quad_mfma(attA, SSb + (size_t)j * 48 * SBP, qA, Rr, lane);
    else
        quad_mfma(attB, IIb + (size_t)i * 48 * SBP, qB, Ww, lane);

    // ---- P4: sims + LSE ----
    if (wid == 0) {
        float e1 = 0.f;
        if (lane < Rr) {
            float q = qA[lane] * myinv * myinv;
            float s1 = dot / fmaxf(sqrtf(iid) * sqrtf(fmaxf(q, 0.f)), EPSf);
            e1 = __expf(6.f * s1);
        }
#pragma unroll
        for (int off = 1; off < 64; off <<= 1) e1 += __shfl_xor(e1, off);
        if (lane == 0) score1[i * Bn + j] = __logf(e1) * (1.f / 6.f);
    } else {
        float e2 = 0.f;
        if (lane < Ww) {
            float q = qB[lane] * myinv * myinv;
            float s2 = dot / fmaxf(sqrtf(ssd) * sqrtf(fmaxf(q, 0.f)), EPSf);
            e2 = (lane < L) ? __expf(6.f * s2) : 0.f;
        }
#pragma unroll
        for (int off = 1; off < 64; off <<= 1) e2 += __shfl_xor(e2, off);
        if (lane == 0) score2[i * Bn + j] = __logf(e2) * (1.f / 6.f);
    }

    // ---- diag coefficients (block-uniform branch) ----
    if (i == j) {
        __syncthreads();
        if (wid == 1 && lane < Ww) {
            float sum = 0.f;
#pragma unroll 6
            for (int r = 0; r < Rr; ++r) sum += bf2f(attA[r * PAD + lane]) * sA[r];
            dAp[i * Ww + lane] = sum * (1.f / (float)Rr);
        }
        if (wid == 0 && lane < Rr) {
            float sum = 0.f;
            for (int w = 0; w < L; ++w) sum += bf2f(attB[w * PAD + lane]) * sB[w];
            dBp[i * Rr + lane] = sum / (float)L;
        }
    }
}

// ================= diagonal outputs + fused hinge loss =================
__global__ __launch_bounds__(256) void diag_out_kernel(const u16* __restrict__ Ab,
                                                       const u16* __restrict__ Bb,
                                                       const int* __restrict__ s_l,
                                                       const float* __restrict__ dA,
                                                       const float* __restrict__ dB,
                                                       const float* __restrict__ score1,
                                                       const float* __restrict__ score2,
                                                       float* __restrict__ out) {
    int t = threadIdx.x;
    if (blockIdx.y == 4) {
        if (blockIdx.x != 0) return;
        __shared__ float sc[Bn][Bn + 1];
        for (int idx = t; idx < Bn * Bn; idx += 256)
            sc[idx >> 6][idx & 63] = 0.5f * (score1[idx] + score2[idx]);
        __syncthreads();
        if (t < 64) {
            float dt = sc[t][t];
            float rowmax = 0.f, colmax = 0.f;
            for (int k = 0; k < Bn; ++k) {
                if (k != t) {
                    rowmax = fmaxf(rowmax, 0.2f + sc[t][k] - dt);
                    colmax = fmaxf(colmax, 0.2f + sc[k][t] - dt);
                }
            }
            float v = rowmax + colmax;
            for (int off = 32; off; off >>= 1) v += __shfl_down(v, off);
            if (t == 0) out[0] = v;
        }
        return;
    }
    int i = blockIdx.x;
    int d = blockIdx.y * 256 + t;
    int L = s_l[i];
    __shared__ float aw[Ww], br[Rr];
    if (t < Ww) aw[t] = dA[i * Ww + t];
    if (t >= 64 && t < 64 + Rr) br[t - 64] = dB[i * Rr + (t - 64)];
    __syncthreads();
    float acc1 = 0.f;
    for (int w = 0; w < L; ++w) acc1 += aw[w] * bf2f(Bb[((size_t)i * Ww + w) * Dd + d]);
    out[1 + (size_t)i * Dd + d] = acc1;
    float acc2 = 0.f;
    for (int r = 0; r < Rr; ++r) acc2 += br[r] * bf2f(Ab[((size_t)i * Rr + r) * Dd + d]);
    out[1 + (size_t)Bn * Dd + (size_t)i * Dd + d] = acc2;
}

extern "C" void kernel_launch(void* const* d_in, const int* in_sizes, int n_in,
                              void* d_out, int out_size, void* d_ws, size_t ws_size,
                              hipStream_t stream) {
    const float* im = (const float*)d_in[0];
    const float* s = (const float*)d_in[1];
    const int* s_l = (const int*)d_in[2];
    float* out = (float*)d_out;

    u16* Ab = (u16*)d_ws;                         // GM*Dd
    u16* Bb = Ab + (size_t)GM * Dd;               // GN*Dd
    u16* Gb = Bb + (size_t)GN * Dd;               // GM*GN
    u16* SSb = Gb + (size_t)GM * GN;              // 64*48*64
    u16* IIb = SSb + (size_t)Bn * 48 * SBP;       // 64*48*64
    float* SSd = (float*)(IIb + (size_t)Bn * 48 * SBP);
    float* IId = SSd + (size_t)Bn * Ww;
    float* score1 = IId + (size_t)Bn * Rr;
    float* score2 = score1 + Bn * Bn;
    float* dA = score2 + Bn * Bn;
    float* dB = dA + Bn * Ww;

    prep_kernel<<<NCONV + 2 * Bn, 256, 0, stream>>>(im, s, s_l, Ab, Bb, SSb, IIb, SSd, IId);

    dim3 ggrid(GN / 128, GM / 64);
    gemm_mfma_kernel<<<ggrid, 256, 0, stream>>>(Ab, Bb, Gb);

    dim3 pgrid(Bn, Bn);
    pair_kernel<<<pgrid, 128, 0, stream>>>(Gb, SSb, IIb, SSd, IId, s_l,
                                           score1, score2, dA, dB);

    dim3 dgrid(Bn, 5);
    diag_out_kernel<<<dgrid, 256, 0, stream>>>(Ab, Bb, s_l, dA, dB, score1, score2, out);
}